// Round 3
// 345.306 us; speedup vs baseline: 1.0289x; 1.0289x over previous
//
#include <hip/hip_runtime.h>

// data: [4, 3, 1024, 1024] fp32; NX=64, scale=16, ny=64, N=4096, p=15
// out = concat(A[4,4096,4096], data) flat fp32
//
// A is banded: row n has nonzeros only at cols n-64, n-1, n+1, n+64.
// Strategy: NO memset (the runtime fill ran at ~1.3 TB/s effective, 207us).
// One block per A-row: 4 waves compute the row's <=4 incident edge values
// (bit-identical summation order across both incident rows -> symmetric
// pairs match exactly), then the block streams the 16KB row once with
// nontemporal 16B stores, patching band elements in-register. Every A byte
// is written exactly once at streaming rate.
//
// Fix vs last round: __builtin_nontemporal_store requires a clang
// ext_vector pointer, not HIP's float4 class -> use floatx4 alias.
#define BB 4
#define CC 3
#define HH 1024
#define WW 1024
#define NXG 64
#define SCALE 16
#define PP 15
#define NNODE 4096

typedef float floatx4 __attribute__((ext_vector_type(4)));

static const long long A_ELEMS    = (long long)BB * NNODE * NNODE;   // 67,108,864
static const long long DATA_ELEMS = (long long)BB * CC * HH * WW;    // 12,582,912

#define COPY_BLOCKS 512
#define ROW_BLOCKS  (BB * NNODE)   // 16384 row blocks, one per (b, n)

__global__ __launch_bounds__(256) void fused_band_fill(const float* __restrict__ data,
                                                       float* __restrict__ out) {
    if (blockIdx.x < COPY_BLOCKS) {
        // data -> out tail. nt stores: tail is never re-read. Plain loads:
        // keep data hot in L2/L3 for the edge gathers below.
        long long i = (long long)blockIdx.x * 256 + threadIdx.x;
        const long long stride = (long long)COPY_BLOCKS * 256;
        const floatx4* __restrict__ src = (const floatx4*)data;
        floatx4* dst = (floatx4*)(out + A_ELEMS);
        const long long nvec = DATA_ELEMS / 4;
        for (; i < nvec; i += stride) {
            floatx4 v = src[i];
            __builtin_nontemporal_store(v, dst + i);
        }
        return;
    }

    const int rb = blockIdx.x - COPY_BLOCKS;   // 0..16383
    const int b  = rb >> 12;                   // batch
    const int n  = rb & (NNODE - 1);           // node/row id
    const int y  = n >> 6;
    const int x  = n & 63;

    const int w    = threadIdx.x >> 6;         // wave: 0=up 1=down 2=left 3=right
    const int lane = threadIdx.x & 63;
    const int r    = lane >> 2;                // patch row 0..15 (15 inactive)
    const int q    = lane & 3;                 // float4 quad in the 16-wide cell

    bool valid; int gy, gx; long long delta;
    switch (w) {
        case 0:  valid = (y > 0);  gy = y - 1; gx = x;     delta = (long long)SCALE * WW; break;
        case 1:  valid = (y < 63); gy = y;     gx = x;     delta = (long long)SCALE * WW; break;
        case 2:  valid = (x > 0);  gy = y;     gx = x - 1; delta = SCALE;                 break;
        default: valid = (x < 63); gy = y;     gx = x;     delta = SCALE;                 break;
    }

    // Edge computed redundantly by both incident rows, but with identical
    // lane layout and reduction order -> bit-identical, symmetry exact.
    float s = 0.f;
    if (valid && r < PP) {
        const float* p0 = data + (((long long)(b * CC)) * HH + (long long)(gy * SCALE + r)) * WW
                               + gx * SCALE + q * 4;
        #pragma unroll
        for (int c = 0; c < CC; ++c) {
            const float* p = p0 + (long long)c * HH * WW;
            const floatx4 a  = *(const floatx4*)p;
            const floatx4 nb = *(const floatx4*)(p + delta);
            float d = fabsf(nb.x - a.x) + fabsf(nb.y - a.y) + fabsf(nb.z - a.z);
            if (q != 3) d += fabsf(nb.w - a.w);   // col 15 excluded
            s += d;
        }
    }
    #pragma unroll
    for (int off = 32; off; off >>= 1) s += __shfl_down(s, off, 64);

    __shared__ float ev[4];
    if (lane == 0) ev[w] = s;
    __syncthreads();

    const float v_up = ev[0], v_dn = ev[1], v_lf = ev[2], v_rt = ev[3];
    // Sentinel -1 for nonexistent neighbors: never matches a col in [0,4096).
    const int c_up = (y > 0)  ? n - NXG : -1;
    const int c_dn = (y < 63) ? n + NXG : -1;
    const int c_lf = (x > 0)  ? n - 1   : -1;
    const int c_rt = (x < 63) ? n + 1   : -1;

    float* rowp = out + ((long long)b * NNODE + n) * NNODE;
    #pragma unroll
    for (int k = 0; k < 4; ++k) {
        const int cb = (int)(threadIdx.x + k * 256) << 2;   // col base of this quad
        const int c0 = cb, c1 = cb + 1, c2 = cb + 2, c3 = cb + 3;
        floatx4 v;
        v.x = (c0 == c_up) ? v_up : (c0 == c_dn) ? v_dn : (c0 == c_lf) ? v_lf : (c0 == c_rt) ? v_rt : 0.f;
        v.y = (c1 == c_up) ? v_up : (c1 == c_dn) ? v_dn : (c1 == c_lf) ? v_lf : (c1 == c_rt) ? v_rt : 0.f;
        v.z = (c2 == c_up) ? v_up : (c2 == c_dn) ? v_dn : (c2 == c_lf) ? v_lf : (c2 == c_rt) ? v_rt : 0.f;
        v.w = (c3 == c_up) ? v_up : (c3 == c_dn) ? v_dn : (c3 == c_lf) ? v_lf : (c3 == c_rt) ? v_rt : 0.f;
        __builtin_nontemporal_store(v, (floatx4*)(rowp + cb));
    }
}

extern "C" void kernel_launch(void* const* d_in, const int* in_sizes, int n_in,
                              void* d_out, int out_size, void* d_ws, size_t ws_size,
                              hipStream_t stream) {
    const float* data = (const float*)d_in[0];
    float* out = (float*)d_out;
    fused_band_fill<<<COPY_BLOCKS + ROW_BLOCKS, 256, 0, stream>>>(data, out);
}